// Round 3
// baseline (231.146 us; speedup 1.0000x reference)
//
#include <hip/hip_runtime.h>

#define LOSS_EPS 0.001f
#define EPS_PAR 1e-12f
#define EPS_PT 1e-12f

struct V3 { float x, y, z; };

__device__ __forceinline__ V3 operator-(V3 a, V3 b) { return {a.x - b.x, a.y - b.y, a.z - b.z}; }
__device__ __forceinline__ V3 operator+(V3 a, V3 b) { return {a.x + b.x, a.y + b.y, a.z + b.z}; }
__device__ __forceinline__ V3 operator*(float s, V3 a) { return {s * a.x, s * a.y, s * a.z}; }
__device__ __forceinline__ float dot(V3 a, V3 b) { return a.x * b.x + a.y * b.y + a.z * b.z; }
__device__ __forceinline__ float clamp01(float v) { return fminf(fmaxf(v, 0.0f), 1.0f); }
__device__ __forceinline__ float frcp(float x) { return __builtin_amdgcn_rcpf(x); }

__device__ __forceinline__ float edge_edge_d2(V3 p1, V3 d1, V3 p2, V3 d2,
                                              float a, float e, float ra, float re) {
    V3 r = p1 - p2;
    float f = dot(d2, r);
    float b = dot(d1, d2);
    float c = dot(d1, r);
    float denom = a * e - b * b;
    bool parallel = denom < EPS_PAR;
    float rd = frcp(parallel ? 1.0f : denom);
    float s = (b * f - c * e) * rd;
    float t = (a * f - b * c) * rd;
    s = parallel ? 0.0f : s;
    float s_cl = clamp01(s);
    float t_cl = clamp01(t);
    bool recompute_t = (s_cl != s) || parallel;
    V3 r_new = r + s_cl * d1;
    float t_new = clamp01(dot(r_new, d2) * re);
    float t_fin = recompute_t ? t_new : t_cl;
    bool recompute_s = (t_cl != t) && (!parallel) && (s_cl == s);
    V3 r_new2 = r - t_fin * d2;
    float s_new = (-dot(r_new2, d1)) * ra;
    float s_fin = recompute_s ? clamp01(s_new) : s_cl;
    V3 c1 = p1 + s_fin * d1;
    V3 c2 = p2 + t_fin * d2;
    V3 diff = c1 - c2;
    return dot(diff, diff);
}

__device__ __forceinline__ float ptri3_min_d2(V3 p0, V3 p1, V3 p2,
                                              V3 v0, V3 v1, V3 v2) {
    V3 e0 = v1 - v0;
    V3 e1 = v2 - v0;
    V3 e2t = v2 - v1;
    float a  = fmaxf(dot(e0, e0), EPS_PT);
    float b  = dot(e0, e1);
    float c  = fmaxf(dot(e1, e1), EPS_PT);
    float a2 = fmaxf(dot(e2t, e2t), EPS_PT);
    float det = fmaxf(a * c - b * b, EPS_PT);
    float ra = frcp(a), rc = frcp(c), ra2 = frcp(a2), rdet = frcp(det);

    float best = 1e30f;
    V3 pts[3] = {p0, p1, p2};
#pragma unroll
    for (int k = 0; k < 3; ++k) {
        V3 p = pts[k];
        V3 w = p - v0;
        float d = dot(e0, w);
        float e = dot(e1, w);
        float f = dot(w, w);
        float s = b * e - c * d;
        float t = b * d - a * e;
        bool in_face = (s >= 0.0f) && (t >= 0.0f) && (s + t <= det);
        float s01 = clamp01(d * ra);
        V3 u01 = w - s01 * e0;
        float d2_e01 = dot(u01, u01);
        float t02 = clamp01(e * rc);
        V3 u02 = w - t02 * e1;
        float d2_e02 = dot(u02, u02);
        V3 w2 = p - v1;
        float dd2 = dot(e2t, w2);
        float u12 = clamp01(dd2 * ra2);
        V3 u12v = w2 - u12 * e2t;
        float d2_e12 = dot(u12v, u12v);
        float d2_face = fmaxf((f * det - (d * s + e * t)) * rdet, 0.0f);
        float d2_edge = fminf(fminf(d2_e01, d2_e02), d2_e12);
        best = fminf(best, in_face ? d2_face : d2_edge);
    }
    return best;
}

// Shared per-pair body given the 18 raw floats.
__device__ __forceinline__ void pair_body(const float t1[9], const float t2[9],
                                          float val, float& pen) {
    V3 A[3]  = { {t1[0], t1[1], t1[2]}, {t1[3], t1[4], t1[5]}, {t1[6], t1[7], t1[8]} };
    V3 Ac[3] = { {t1[0], t1[3], t1[6]}, {t1[1], t1[4], t1[7]}, {t1[2], t1[5], t1[8]} };
    V3 B[3]  = { {t2[0], t2[1], t2[2]}, {t2[3], t2[4], t2[5]}, {t2[6], t2[7], t2[8]} };
    V3 Bc[3] = { {t2[0], t2[3], t2[6]}, {t2[1], t2[4], t2[7]}, {t2[2], t2[5], t2[8]} };

    float mind2 = 1e30f;
    mind2 = fminf(mind2, ptri3_min_d2(A[0], A[1], A[2], Bc[0], Bc[1], Bc[2]));
    mind2 = fminf(mind2, ptri3_min_d2(B[0], B[1], B[2], Ac[0], Ac[1], Ac[2]));

    V3 dA[3] = { A[1] - A[0], A[2] - A[1], A[0] - A[2] };
    V3 dB[3] = { B[1] - B[0], B[2] - B[1], B[0] - B[2] };
    float la[3], lb[3], rla[3], rlb[3];
#pragma unroll
    for (int k = 0; k < 3; ++k) {
        la[k] = dot(dA[k], dA[k]); rla[k] = frcp(la[k]);
        lb[k] = dot(dB[k], dB[k]); rlb[k] = frcp(lb[k]);
    }
#pragma unroll
    for (int ii = 0; ii < 3; ++ii) {
#pragma unroll
        for (int jj = 0; jj < 3; ++jj) {
            mind2 = fminf(mind2, edge_edge_d2(A[ii], dA[ii], B[jj], dB[jj],
                                              la[ii], lb[jj], rla[ii], rlb[jj]));
        }
    }
    float dist = sqrtf(mind2);
    pen = fmaxf(LOSS_EPS - dist, 0.0f) * val;
}

__device__ __forceinline__ void block_reduce_atomic(float pen, float val, float* ws) {
#pragma unroll
    for (int off = 32; off > 0; off >>= 1) {
        pen += __shfl_down(pen, off);
        val += __shfl_down(val, off);
    }
    __shared__ float sp[4], sv[4];
    int wid = threadIdx.x >> 6;
    if ((threadIdx.x & 63) == 0) { sp[wid] = pen; sv[wid] = val; }
    __syncthreads();
    if (threadIdx.x == 0) {
        atomicAdd(&ws[0], sp[0] + sp[1] + sp[2] + sp[3]);
        atomicAdd(&ws[1], sv[0] + sv[1] + sv[2] + sv[3]);
    }
}

// Repack 9-float (36B, 4B-aligned) triangles into 64B-aligned 4xfloat4 slots.
__global__ void __launch_bounds__(256)
prep_kernel(const float* __restrict__ tris, float4* __restrict__ pack, int ntri) {
    int g = blockIdx.x * 256 + threadIdx.x;
    if (g >= ntri) return;
    const float* s = tris + (size_t)g * 9;
    float t[9];
#pragma unroll
    for (int k = 0; k < 9; ++k) t[k] = s[k];
    float4* d = pack + (size_t)g * 4;
    d[0] = make_float4(t[0], t[1], t[2], t[3]);
    d[1] = make_float4(t[4], t[5], t[6], t[7]);
    d[2] = make_float4(t[8], 0.0f, 0.0f, 0.0f);
    // d[3] unused padding (never read)
}

__global__ void __launch_bounds__(256)
pen_loss_packed(const float4* __restrict__ pack, const int2* __restrict__ idx,
                float* __restrict__ ws, int npairs, int F, int P, int nwg) {
    // Bijective XCD chunk swizzle: physical block pb (assumed XCD = pb%8)
    // -> logical block lb so each XCD covers a contiguous chunk (one batch's table).
    int pb = blockIdx.x;
    int x = pb & 7;
    int j = pb >> 3;
    int q = nwg >> 3, r = nwg & 7;
    int start = (x < r) ? x * (q + 1) : r * (q + 1) + (x - r) * q;
    int i = (start + j) * 256 + (int)threadIdx.x;

    float pen = 0.0f, val = 0.0f;
    if (i < npairs) {
        int b = i / P;
        int2 ij = idx[i];
        val = (ij.x >= 0) ? 1.0f : 0.0f;
        size_t base = (size_t)b * (size_t)F;
        size_t o1 = (base + (size_t)max(ij.x, 0)) * 4;
        size_t o2 = (base + (size_t)max(ij.y, 0)) * 4;
        float4 a0 = pack[o1], a1 = pack[o1 + 1], a2 = pack[o1 + 2];
        float4 b0 = pack[o2], b1 = pack[o2 + 1], b2 = pack[o2 + 2];
        float t1[9] = {a0.x, a0.y, a0.z, a0.w, a1.x, a1.y, a1.z, a1.w, a2.x};
        float t2[9] = {b0.x, b0.y, b0.z, b0.w, b1.x, b1.y, b1.z, b1.w, b2.x};
        pair_body(t1, t2, val, pen);
    }
    block_reduce_atomic(pen, val, ws);
}

// Fallback (no workspace): round-2 style direct loads.
__global__ void __launch_bounds__(256)
pen_loss_direct(const float* __restrict__ tris, const int2* __restrict__ idx,
                float* __restrict__ ws, int npairs, int F, int P) {
    int i = blockIdx.x * 256 + threadIdx.x;
    float pen = 0.0f, val = 0.0f;
    if (i < npairs) {
        int b = i / P;
        int2 ij = idx[i];
        val = (ij.x >= 0) ? 1.0f : 0.0f;
        const float* T1 = tris + ((size_t)b * (size_t)F + (size_t)max(ij.x, 0)) * 9;
        const float* T2 = tris + ((size_t)b * (size_t)F + (size_t)max(ij.y, 0)) * 9;
        float t1[9], t2[9];
#pragma unroll
        for (int k = 0; k < 9; ++k) t1[k] = T1[k];
#pragma unroll
        for (int k = 0; k < 9; ++k) t2[k] = T2[k];
        pair_body(t1, t2, val, pen);
    }
    block_reduce_atomic(pen, val, ws);
}

__global__ void finalize_kernel(const float* __restrict__ ws, float* __restrict__ out) {
    out[0] = ws[0] / fmaxf(ws[1], 1.0f);
}

extern "C" void kernel_launch(void* const* d_in, const int* in_sizes, int n_in,
                              void* d_out, int out_size, void* d_ws, size_t ws_size,
                              hipStream_t stream) {
    const float* tris = (const float*)d_in[0];
    const int* idx = (const int*)d_in[1];
    float* out = (float*)d_out;
    float* ws = (float*)d_ws;

    const int B = 4;
    int F = in_sizes[0] / (B * 9);      // 50000
    int npairs = in_sizes[1] / 2;       // 2,000,000
    int P = npairs / B;                 // 500,000
    int ntri = B * F;                   // 200,000

    hipMemsetAsync(d_ws, 0, 2 * sizeof(float), stream);
    int nwg = (npairs + 255) / 256;

    size_t need = 256 + (size_t)ntri * 64;
    if (ws_size >= need) {
        float4* pack = (float4*)((char*)d_ws + 256);
        prep_kernel<<<(ntri + 255) / 256, 256, 0, stream>>>(tris, pack, ntri);
        pen_loss_packed<<<nwg, 256, 0, stream>>>(pack, (const int2*)idx, ws,
                                                 npairs, F, P, nwg);
    } else {
        pen_loss_direct<<<nwg, 256, 0, stream>>>(tris, (const int2*)idx, ws,
                                                 npairs, F, P);
    }
    finalize_kernel<<<1, 1, 0, stream>>>(ws, out);
}

// Round 4
// 92.759 us; speedup vs baseline: 2.4919x; 2.4919x over previous
//
#include <hip/hip_runtime.h>

#define LOSS_EPS 0.001f
#define EPS_PAR 1e-12f
#define EPS_PT 1e-12f

struct V3 { float x, y, z; };

__device__ __forceinline__ V3 operator-(V3 a, V3 b) { return {a.x - b.x, a.y - b.y, a.z - b.z}; }
__device__ __forceinline__ V3 operator+(V3 a, V3 b) { return {a.x + b.x, a.y + b.y, a.z + b.z}; }
__device__ __forceinline__ V3 operator*(float s, V3 a) { return {s * a.x, s * a.y, s * a.z}; }
__device__ __forceinline__ float dot(V3 a, V3 b) { return a.x * b.x + a.y * b.y + a.z * b.z; }
__device__ __forceinline__ float clamp01(float v) { return fminf(fmaxf(v, 0.0f), 1.0f); }
__device__ __forceinline__ float frcp(float x) { return __builtin_amdgcn_rcpf(x); }

__device__ __forceinline__ float edge_edge_d2(V3 p1, V3 d1, V3 p2, V3 d2,
                                              float a, float e, float ra, float re) {
    V3 r = p1 - p2;
    float f = dot(d2, r);
    float b = dot(d1, d2);
    float c = dot(d1, r);
    float denom = a * e - b * b;
    bool parallel = denom < EPS_PAR;
    float rd = frcp(parallel ? 1.0f : denom);
    float s = (b * f - c * e) * rd;
    float t = (a * f - b * c) * rd;
    s = parallel ? 0.0f : s;
    float s_cl = clamp01(s);
    float t_cl = clamp01(t);
    bool recompute_t = (s_cl != s) || parallel;
    V3 r_new = r + s_cl * d1;
    float t_new = clamp01(dot(r_new, d2) * re);
    float t_fin = recompute_t ? t_new : t_cl;
    bool recompute_s = (t_cl != t) && (!parallel) && (s_cl == s);
    V3 r_new2 = r - t_fin * d2;
    float s_new = (-dot(r_new2, d1)) * ra;
    float s_fin = recompute_s ? clamp01(s_new) : s_cl;
    V3 c1 = p1 + s_fin * d1;
    V3 c2 = p2 + t_fin * d2;
    V3 diff = c1 - c2;
    return dot(diff, diff);
}

__device__ __forceinline__ float ptri3_min_d2(V3 p0, V3 p1, V3 p2,
                                              V3 v0, V3 v1, V3 v2) {
    V3 e0 = v1 - v0;
    V3 e1 = v2 - v0;
    V3 e2t = v2 - v1;
    float a  = fmaxf(dot(e0, e0), EPS_PT);
    float b  = dot(e0, e1);
    float c  = fmaxf(dot(e1, e1), EPS_PT);
    float a2 = fmaxf(dot(e2t, e2t), EPS_PT);
    float det = fmaxf(a * c - b * b, EPS_PT);
    float ra = frcp(a), rc = frcp(c), ra2 = frcp(a2), rdet = frcp(det);

    float best = 1e30f;
    V3 pts[3] = {p0, p1, p2};
#pragma unroll
    for (int k = 0; k < 3; ++k) {
        V3 p = pts[k];
        V3 w = p - v0;
        float d = dot(e0, w);
        float e = dot(e1, w);
        float f = dot(w, w);
        float s = b * e - c * d;
        float t = b * d - a * e;
        bool in_face = (s >= 0.0f) && (t >= 0.0f) && (s + t <= det);
        float s01 = clamp01(d * ra);
        V3 u01 = w - s01 * e0;
        float d2_e01 = dot(u01, u01);
        float t02 = clamp01(e * rc);
        V3 u02 = w - t02 * e1;
        float d2_e02 = dot(u02, u02);
        V3 w2 = p - v1;
        float dd2 = dot(e2t, w2);
        float u12 = clamp01(dd2 * ra2);
        V3 u12v = w2 - u12 * e2t;
        float d2_e12 = dot(u12v, u12v);
        float d2_face = fmaxf((f * det - (d * s + e * t)) * rdet, 0.0f);
        float d2_edge = fminf(fminf(d2_e01, d2_e02), d2_e12);
        best = fminf(best, in_face ? d2_face : d2_edge);
    }
    return best;
}

__device__ __forceinline__ float pair_body(const float t1[9], const float t2[9], float val) {
    V3 A[3]  = { {t1[0], t1[1], t1[2]}, {t1[3], t1[4], t1[5]}, {t1[6], t1[7], t1[8]} };
    V3 Ac[3] = { {t1[0], t1[3], t1[6]}, {t1[1], t1[4], t1[7]}, {t1[2], t1[5], t1[8]} };
    V3 B[3]  = { {t2[0], t2[1], t2[2]}, {t2[3], t2[4], t2[5]}, {t2[6], t2[7], t2[8]} };
    V3 Bc[3] = { {t2[0], t2[3], t2[6]}, {t2[1], t2[4], t2[7]}, {t2[2], t2[5], t2[8]} };

    float mind2 = 1e30f;
    mind2 = fminf(mind2, ptri3_min_d2(A[0], A[1], A[2], Bc[0], Bc[1], Bc[2]));
    mind2 = fminf(mind2, ptri3_min_d2(B[0], B[1], B[2], Ac[0], Ac[1], Ac[2]));

    V3 dA[3] = { A[1] - A[0], A[2] - A[1], A[0] - A[2] };
    V3 dB[3] = { B[1] - B[0], B[2] - B[1], B[0] - B[2] };
    float la[3], lb[3], rla[3], rlb[3];
#pragma unroll
    for (int k = 0; k < 3; ++k) {
        la[k] = dot(dA[k], dA[k]); rla[k] = frcp(la[k]);
        lb[k] = dot(dB[k], dB[k]); rlb[k] = frcp(lb[k]);
    }
#pragma unroll
    for (int ii = 0; ii < 3; ++ii) {
#pragma unroll
        for (int jj = 0; jj < 3; ++jj) {
            mind2 = fminf(mind2, edge_edge_d2(A[ii], dA[ii], B[jj], dB[jj],
                                              la[ii], lb[jj], rla[ii], rlb[jj]));
        }
    }
    float dist = sqrtf(mind2);
    return fmaxf(LOSS_EPS - dist, 0.0f) * val;
}

__device__ __forceinline__ void block_reduce_atomic(float pen, float val, float* ws) {
#pragma unroll
    for (int off = 32; off > 0; off >>= 1) {
        pen += __shfl_down(pen, off);
        val += __shfl_down(val, off);
    }
    __shared__ float sp[4], sv[4];
    int wid = threadIdx.x >> 6;
    if ((threadIdx.x & 63) == 0) { sp[wid] = pen; sv[wid] = val; }
    __syncthreads();
    if (threadIdx.x == 0) {
        atomicAdd(&ws[0], sp[0] + sp[1] + sp[2] + sp[3]);
        atomicAdd(&ws[1], sv[0] + sv[1] + sv[2] + sv[3]);
    }
}

// Repack 9-float (36B) triangles into 64B-aligned slots (3 float4 used, 1 pad).
__global__ void __launch_bounds__(256)
prep_kernel(const float* __restrict__ tris, float4* __restrict__ pack, int ntri) {
    int g = blockIdx.x * 256 + threadIdx.x;
    if (g >= ntri) return;
    const float* s = tris + (size_t)g * 9;
    float t[9];
#pragma unroll
    for (int k = 0; k < 9; ++k) t[k] = s[k];
    float4* d = pack + (size_t)g * 4;
    d[0] = make_float4(t[0], t[1], t[2], t[3]);
    d[1] = make_float4(t[4], t[5], t[6], t[7]);
    d[2] = make_float4(t[8], 0.0f, 0.0f, 0.0f);
}

#define PAIRS_PER_BLOCK 1024  // 4 per thread

__global__ void __launch_bounds__(256)
pen_loss_pipelined(const float4* __restrict__ pack, const int2* __restrict__ idx,
                   float* __restrict__ ws, int npairs, int F, int P, int nwg) {
    // Bijective XCD chunk swizzle (m204): XCD x = pb%8 gets a contiguous block range.
    int pb = blockIdx.x;
    int x = pb & 7, j = pb >> 3;
    int q = nwg >> 3, r = nwg & 7;
    int start = (x < r) ? x * (q + 1) : r * (q + 1) + (x - r) * q;
    int lb = start + j;
    int tid = (int)threadIdx.x;
    int p0 = lb * PAIRS_PER_BLOCK + tid;

    // 1) All 4 idx loads in flight upfront (coalesced).
    int ro[4], to[4];
    float vmask[4];
#pragma unroll
    for (int k = 0; k < 4; ++k) {
        int p = p0 + k * 256;
        bool ok = p < npairs;
        int2 ij = ok ? idx[p] : make_int2(0, 0);
        vmask[k] = (ok && ij.x >= 0) ? 1.0f : 0.0f;
        int b = ok ? (p / P) : 0;
        int base = b * F;
        ro[k] = (base + max(ij.x, 0)) * 4;
        to[k] = (base + max(ij.y, 0)) * 4;
    }

    // 2) Software-pipelined gathers, double-buffered in registers.
    float4 ga[2][3], gb[2][3];
    ga[0][0] = pack[ro[0]]; ga[0][1] = pack[ro[0] + 1]; ga[0][2] = pack[ro[0] + 2];
    gb[0][0] = pack[to[0]]; gb[0][1] = pack[to[0] + 1]; gb[0][2] = pack[to[0] + 2];

    float pen_s = 0.0f, val_s = 0.0f;
#pragma unroll
    for (int k = 0; k < 4; ++k) {
        const int cur = k & 1, nxt = cur ^ 1;
        if (k < 3) {
            ga[nxt][0] = pack[ro[k + 1]]; ga[nxt][1] = pack[ro[k + 1] + 1]; ga[nxt][2] = pack[ro[k + 1] + 2];
            gb[nxt][0] = pack[to[k + 1]]; gb[nxt][1] = pack[to[k + 1] + 1]; gb[nxt][2] = pack[to[k + 1] + 2];
        }
        float t1[9] = {ga[cur][0].x, ga[cur][0].y, ga[cur][0].z, ga[cur][0].w,
                       ga[cur][1].x, ga[cur][1].y, ga[cur][1].z, ga[cur][1].w, ga[cur][2].x};
        float t2[9] = {gb[cur][0].x, gb[cur][0].y, gb[cur][0].z, gb[cur][0].w,
                       gb[cur][1].x, gb[cur][1].y, gb[cur][1].z, gb[cur][1].w, gb[cur][2].x};
        pen_s += pair_body(t1, t2, vmask[k]);
        val_s += vmask[k];
    }
    block_reduce_atomic(pen_s, val_s, ws);
}

// Fallback (workspace too small): direct loads, one pair per thread.
__global__ void __launch_bounds__(256)
pen_loss_direct(const float* __restrict__ tris, const int2* __restrict__ idx,
                float* __restrict__ ws, int npairs, int F, int P) {
    int i = blockIdx.x * 256 + threadIdx.x;
    float pen = 0.0f, val = 0.0f;
    if (i < npairs) {
        int b = i / P;
        int2 ij = idx[i];
        val = (ij.x >= 0) ? 1.0f : 0.0f;
        const float* T1 = tris + ((size_t)b * (size_t)F + (size_t)max(ij.x, 0)) * 9;
        const float* T2 = tris + ((size_t)b * (size_t)F + (size_t)max(ij.y, 0)) * 9;
        float t1[9], t2[9];
#pragma unroll
        for (int k = 0; k < 9; ++k) t1[k] = T1[k];
#pragma unroll
        for (int k = 0; k < 9; ++k) t2[k] = T2[k];
        pen = pair_body(t1, t2, val);
    }
    block_reduce_atomic(pen, val, ws);
}

__global__ void finalize_kernel(const float* __restrict__ ws, float* __restrict__ out) {
    out[0] = ws[0] / fmaxf(ws[1], 1.0f);
}

extern "C" void kernel_launch(void* const* d_in, const int* in_sizes, int n_in,
                              void* d_out, int out_size, void* d_ws, size_t ws_size,
                              hipStream_t stream) {
    const float* tris = (const float*)d_in[0];
    const int* idx = (const int*)d_in[1];
    float* out = (float*)d_out;
    float* ws = (float*)d_ws;

    const int B = 4;
    int F = in_sizes[0] / (B * 9);      // 50000
    int npairs = in_sizes[1] / 2;       // 2,000,000
    int P = npairs / B;                 // 500,000
    int ntri = B * F;                   // 200,000

    hipMemsetAsync(d_ws, 0, 2 * sizeof(float), stream);

    size_t need = 256 + (size_t)ntri * 64;
    if (ws_size >= need) {
        float4* pack = (float4*)((char*)d_ws + 256);
        prep_kernel<<<(ntri + 255) / 256, 256, 0, stream>>>(tris, pack, ntri);
        int nwg = (npairs + PAIRS_PER_BLOCK - 1) / PAIRS_PER_BLOCK;   // 1954
        pen_loss_pipelined<<<nwg, 256, 0, stream>>>(pack, (const int2*)idx, ws,
                                                    npairs, F, P, nwg);
    } else {
        int nwg = (npairs + 255) / 256;
        pen_loss_direct<<<nwg, 256, 0, stream>>>(tris, (const int2*)idx, ws,
                                                 npairs, F, P);
    }
    finalize_kernel<<<1, 1, 0, stream>>>(ws, out);
}

// Round 5
// 91.446 us; speedup vs baseline: 2.5277x; 1.0144x over previous
//
#include <hip/hip_runtime.h>

#define LOSS_EPS 0.001f
#define EPS_PAR 1e-12f
#define EPS_PT 1e-12f

typedef float f32x2 __attribute__((ext_vector_type(2)));
typedef int   i32x2 __attribute__((ext_vector_type(2)));

__device__ __forceinline__ f32x2 vmin2(f32x2 a, f32x2 b) { return __builtin_elementwise_min(a, b); }
__device__ __forceinline__ f32x2 vmax2(f32x2 a, f32x2 b) { return __builtin_elementwise_max(a, b); }
__device__ __forceinline__ f32x2 vclamp01(f32x2 v) {
    return vmin2(vmax2(v, (f32x2)0.0f), (f32x2)1.0f);
}
__device__ __forceinline__ f32x2 vrcp(f32x2 x) {
    f32x2 r; r.x = __builtin_amdgcn_rcpf(x.x); r.y = __builtin_amdgcn_rcpf(x.y); return r;
}
// bit-select: m ? a : b per lane-component (m = -1/0 from vector compare)
__device__ __forceinline__ f32x2 vsel(i32x2 m, f32x2 a, f32x2 b) {
    i32x2 ai = __builtin_bit_cast(i32x2, a);
    i32x2 bi = __builtin_bit_cast(i32x2, b);
    i32x2 r = (ai & m) | (bi & ~m);
    return __builtin_bit_cast(f32x2, r);
}

struct V3p { f32x2 x, y, z; };
__device__ __forceinline__ V3p operator-(V3p a, V3p b) { return {a.x - b.x, a.y - b.y, a.z - b.z}; }
__device__ __forceinline__ V3p operator+(V3p a, V3p b) { return {a.x + b.x, a.y + b.y, a.z + b.z}; }
__device__ __forceinline__ V3p operator*(f32x2 s, V3p a) { return {s * a.x, s * a.y, s * a.z}; }
__device__ __forceinline__ f32x2 dotp(V3p a, V3p b) { return a.x * b.x + a.y * b.y + a.z * b.z; }

__device__ __forceinline__ f32x2 edge_edge_d2(V3p p1, V3p d1, V3p p2, V3p d2,
                                              f32x2 a, f32x2 e, f32x2 ra, f32x2 re) {
    V3p r = p1 - p2;
    f32x2 f = dotp(d2, r);
    f32x2 b = dotp(d1, d2);
    f32x2 c = dotp(d1, r);
    f32x2 denom = a * e - b * b;
    i32x2 par = denom < (f32x2)EPS_PAR;
    f32x2 rd = vrcp(vsel(par, (f32x2)1.0f, denom));
    f32x2 s = (b * f - c * e) * rd;
    f32x2 t = (a * f - b * c) * rd;
    s = vsel(par, (f32x2)0.0f, s);
    f32x2 s_cl = vclamp01(s);
    f32x2 t_cl = vclamp01(t);
    i32x2 rec_t = (s_cl != s) | par;
    V3p r_new = r + s_cl * d1;
    f32x2 t_new = vclamp01(dotp(r_new, d2) * re);
    f32x2 t_fin = vsel(rec_t, t_new, t_cl);
    i32x2 rec_s = (t_cl != t) & ~par & (s_cl == s);
    V3p r_new2 = r - t_fin * d2;
    f32x2 s_new = (-dotp(r_new2, d1)) * ra;
    f32x2 s_fin = vsel(rec_s, vclamp01(s_new), s_cl);
    V3p c1 = p1 + s_fin * d1;
    V3p c2 = p2 + t_fin * d2;
    V3p diff = c1 - c2;
    return dotp(diff, diff);
}

__device__ __forceinline__ f32x2 ptri3_min_d2(V3p p0, V3p p1, V3p p2,
                                              V3p v0, V3p v1, V3p v2) {
    V3p e0 = v1 - v0;
    V3p e1 = v2 - v0;
    V3p e2t = v2 - v1;
    f32x2 a  = vmax2(dotp(e0, e0), (f32x2)EPS_PT);
    f32x2 b  = dotp(e0, e1);
    f32x2 c  = vmax2(dotp(e1, e1), (f32x2)EPS_PT);
    f32x2 a2 = vmax2(dotp(e2t, e2t), (f32x2)EPS_PT);
    f32x2 det = vmax2(a * c - b * b, (f32x2)EPS_PT);
    f32x2 ra = vrcp(a), rc = vrcp(c), ra2 = vrcp(a2), rdet = vrcp(det);

    f32x2 best = (f32x2)1e30f;
    V3p pts[3] = {p0, p1, p2};
#pragma unroll
    for (int k = 0; k < 3; ++k) {
        V3p p = pts[k];
        V3p w = p - v0;
        f32x2 d = dotp(e0, w);
        f32x2 e = dotp(e1, w);
        f32x2 f = dotp(w, w);
        f32x2 s = b * e - c * d;
        f32x2 t = b * d - a * e;
        i32x2 in_face = (s >= (f32x2)0.0f) & (t >= (f32x2)0.0f) & ((s + t) <= det);
        f32x2 s01 = vclamp01(d * ra);
        V3p u01 = w - s01 * e0;
        f32x2 d2_e01 = dotp(u01, u01);
        f32x2 t02 = vclamp01(e * rc);
        V3p u02 = w - t02 * e1;
        f32x2 d2_e02 = dotp(u02, u02);
        V3p w2 = p - v1;
        f32x2 dd2 = dotp(e2t, w2);
        f32x2 u12 = vclamp01(dd2 * ra2);
        V3p u12v = w2 - u12 * e2t;
        f32x2 d2_e12 = dotp(u12v, u12v);
        f32x2 d2_face = vmax2((f * det - (d * s + e * t)) * rdet, (f32x2)0.0f);
        f32x2 d2_edge = vmin2(vmin2(d2_e01, d2_e02), d2_e12);
        best = vmin2(best, vsel(in_face, d2_face, d2_edge));
    }
    return best;
}

// Packed pair body: component 0 = pair A, component 1 = pair B.
// qa/qb: 6 float4 each = triangle1 (3 quads) then triangle2 (3 quads).
__device__ __forceinline__ f32x2 pair_body2(const float4 qa[6], const float4 qb[6], f32x2 vmask) {
    f32x2 T1[9] = {
        {qa[0].x, qb[0].x}, {qa[0].y, qb[0].y}, {qa[0].z, qb[0].z},
        {qa[0].w, qb[0].w}, {qa[1].x, qb[1].x}, {qa[1].y, qb[1].y},
        {qa[1].z, qb[1].z}, {qa[1].w, qb[1].w}, {qa[2].x, qb[2].x}};
    f32x2 T2[9] = {
        {qa[3].x, qb[3].x}, {qa[3].y, qb[3].y}, {qa[3].z, qb[3].z},
        {qa[3].w, qb[3].w}, {qa[4].x, qb[4].x}, {qa[4].y, qb[4].y},
        {qa[4].z, qb[4].z}, {qa[4].w, qb[4].w}, {qa[5].x, qb[5].x}};

    V3p A[3]  = { {T1[0], T1[1], T1[2]}, {T1[3], T1[4], T1[5]}, {T1[6], T1[7], T1[8]} };
    V3p Ac[3] = { {T1[0], T1[3], T1[6]}, {T1[1], T1[4], T1[7]}, {T1[2], T1[5], T1[8]} };
    V3p B[3]  = { {T2[0], T2[1], T2[2]}, {T2[3], T2[4], T2[5]}, {T2[6], T2[7], T2[8]} };
    V3p Bc[3] = { {T2[0], T2[3], T2[6]}, {T2[1], T2[4], T2[7]}, {T2[2], T2[5], T2[8]} };

    f32x2 mind2 = (f32x2)1e30f;
    mind2 = vmin2(mind2, ptri3_min_d2(A[0], A[1], A[2], Bc[0], Bc[1], Bc[2]));
    mind2 = vmin2(mind2, ptri3_min_d2(B[0], B[1], B[2], Ac[0], Ac[1], Ac[2]));

    V3p dA[3] = { A[1] - A[0], A[2] - A[1], A[0] - A[2] };
    V3p dB[3] = { B[1] - B[0], B[2] - B[1], B[0] - B[2] };
    f32x2 la[3], lb[3], rla[3], rlb[3];
#pragma unroll
    for (int k = 0; k < 3; ++k) {
        la[k] = dotp(dA[k], dA[k]); rla[k] = vrcp(la[k]);
        lb[k] = dotp(dB[k], dB[k]); rlb[k] = vrcp(lb[k]);
    }
#pragma unroll
    for (int ii = 0; ii < 3; ++ii) {
#pragma unroll
        for (int jj = 0; jj < 3; ++jj) {
            mind2 = vmin2(mind2, edge_edge_d2(A[ii], dA[ii], B[jj], dB[jj],
                                              la[ii], lb[jj], rla[ii], rlb[jj]));
        }
    }
    f32x2 dist;
    dist.x = __builtin_sqrtf(mind2.x);
    dist.y = __builtin_sqrtf(mind2.y);
    return vmax2((f32x2)LOSS_EPS - dist, (f32x2)0.0f) * vmask;
}

__device__ __forceinline__ void block_reduce_atomic(float pen, float val, float* ws) {
#pragma unroll
    for (int off = 32; off > 0; off >>= 1) {
        pen += __shfl_down(pen, off);
        val += __shfl_down(val, off);
    }
    __shared__ float sp[4], sv[4];
    int wid = threadIdx.x >> 6;
    if ((threadIdx.x & 63) == 0) { sp[wid] = pen; sv[wid] = val; }
    __syncthreads();
    if (threadIdx.x == 0) {
        atomicAdd(&ws[0], sp[0] + sp[1] + sp[2] + sp[3]);
        atomicAdd(&ws[1], sv[0] + sv[1] + sv[2] + sv[3]);
    }
}

// Repack 9-float (36B) triangles into 64B-aligned slots (3 float4 used, 1 pad).
__global__ void __launch_bounds__(256)
prep_kernel(const float* __restrict__ tris, float4* __restrict__ pack, int ntri) {
    int g = blockIdx.x * 256 + threadIdx.x;
    if (g >= ntri) return;
    const float* s = tris + (size_t)g * 9;
    float t[9];
#pragma unroll
    for (int k = 0; k < 9; ++k) t[k] = s[k];
    float4* d = pack + (size_t)g * 4;
    d[0] = make_float4(t[0], t[1], t[2], t[3]);
    d[1] = make_float4(t[4], t[5], t[6], t[7]);
    d[2] = make_float4(t[8], 0.0f, 0.0f, 0.0f);
}

#define PAIRS_PER_BLOCK 1024  // 4 per thread, as 2 packed (2-wide) bodies

__global__ void __launch_bounds__(256)
pen_loss_packed2(const float4* __restrict__ pack, const int2* __restrict__ idx,
                 float* __restrict__ ws, int npairs, int F, int P, int nwg) {
    // Bijective XCD chunk swizzle (m204).
    int pb = blockIdx.x;
    int x = pb & 7, j = pb >> 3;
    int q = nwg >> 3, r = nwg & 7;
    int start = (x < r) ? x * (q + 1) : r * (q + 1) + (x - r) * q;
    int lb = start + j;
    int tid = (int)threadIdx.x;
    int p0 = lb * PAIRS_PER_BLOCK + tid;

    // 1) idx loads for all 4 pairs upfront.
    int o1[4], o2[4];
    float vm[4];
#pragma unroll
    for (int k = 0; k < 4; ++k) {
        int p = p0 + k * 256;
        int pc = min(p, npairs - 1);
        int2 ij = idx[pc];
        vm[k] = (p < npairs && ij.x >= 0) ? 1.0f : 0.0f;
        int b = pc / P;
        int base = b * F;
        o1[k] = (base + max(ij.x, 0)) * 4;
        o2[k] = (base + max(ij.y, 0)) * 4;
    }

    // 2) All 24 dwordx4 gathers in flight.
    float4 g0[6], g1[6], g2[6], g3[6];
#pragma unroll
    for (int t = 0; t < 3; ++t) {
        g0[t] = pack[o1[0] + t]; g0[3 + t] = pack[o2[0] + t];
        g1[t] = pack[o1[1] + t]; g1[3 + t] = pack[o2[1] + t];
        g2[t] = pack[o1[2] + t]; g2[3 + t] = pack[o2[2] + t];
        g3[t] = pack[o1[3] + t]; g3[3 + t] = pack[o2[3] + t];
    }

    // 3) Two packed bodies (pairs 0&1, pairs 2&3).
    f32x2 vm01 = {vm[0], vm[1]};
    f32x2 vm23 = {vm[2], vm[3]};
    f32x2 pen2 = pair_body2(g0, g1, vm01);
    pen2 += pair_body2(g2, g3, vm23);

    float pen_s = pen2.x + pen2.y;
    float val_s = vm[0] + vm[1] + vm[2] + vm[3];
    block_reduce_atomic(pen_s, val_s, ws);
}

// -------- scalar fallback (workspace too small) --------
struct V3 { float x, y, z; };
__device__ __forceinline__ V3 operator-(V3 a, V3 b) { return {a.x - b.x, a.y - b.y, a.z - b.z}; }
__device__ __forceinline__ V3 operator+(V3 a, V3 b) { return {a.x + b.x, a.y + b.y, a.z + b.z}; }
__device__ __forceinline__ V3 operator*(float s, V3 a) { return {s * a.x, s * a.y, s * a.z}; }
__device__ __forceinline__ float dot(V3 a, V3 b) { return a.x * b.x + a.y * b.y + a.z * b.z; }
__device__ __forceinline__ float clamp01(float v) { return fminf(fmaxf(v, 0.0f), 1.0f); }
__device__ __forceinline__ float frcp(float x) { return __builtin_amdgcn_rcpf(x); }

__device__ float pair_body_scalar(const float t1[9], const float t2[9], float val) {
    V3 A[3]  = { {t1[0], t1[1], t1[2]}, {t1[3], t1[4], t1[5]}, {t1[6], t1[7], t1[8]} };
    V3 Ac[3] = { {t1[0], t1[3], t1[6]}, {t1[1], t1[4], t1[7]}, {t1[2], t1[5], t1[8]} };
    V3 B[3]  = { {t2[0], t2[1], t2[2]}, {t2[3], t2[4], t2[5]}, {t2[6], t2[7], t2[8]} };
    V3 Bc[3] = { {t2[0], t2[3], t2[6]}, {t2[1], t2[4], t2[7]}, {t2[2], t2[5], t2[8]} };
    float mind2 = 1e30f;
#pragma unroll
    for (int dir = 0; dir < 2; ++dir) {
        V3* P3 = dir ? B : A;
        V3* T3 = dir ? Ac : Bc;
        V3 e0 = T3[1] - T3[0], e1 = T3[2] - T3[0], e2t = T3[2] - T3[1];
        float a = fmaxf(dot(e0, e0), EPS_PT), b = dot(e0, e1);
        float c = fmaxf(dot(e1, e1), EPS_PT), a2 = fmaxf(dot(e2t, e2t), EPS_PT);
        float det = fmaxf(a * c - b * b, EPS_PT);
        float ra = frcp(a), rc = frcp(c), ra2 = frcp(a2), rdet = frcp(det);
#pragma unroll
        for (int k = 0; k < 3; ++k) {
            V3 p = P3[k];
            V3 w = p - T3[0];
            float d = dot(e0, w), e = dot(e1, w), f = dot(w, w);
            float s = b * e - c * d, t = b * d - a * e;
            bool in_face = (s >= 0.0f) && (t >= 0.0f) && (s + t <= det);
            float s01 = clamp01(d * ra);
            V3 u01 = w - s01 * e0;
            float t02 = clamp01(e * rc);
            V3 u02 = w - t02 * e1;
            V3 w2 = p - T3[1];
            float u12 = clamp01(dot(e2t, w2) * ra2);
            V3 u12v = w2 - u12 * e2t;
            float d2_face = fmaxf((f * det - (d * s + e * t)) * rdet, 0.0f);
            float d2_edge = fminf(fminf(dot(u01, u01), dot(u02, u02)), dot(u12v, u12v));
            mind2 = fminf(mind2, in_face ? d2_face : d2_edge);
        }
    }
    V3 dA[3] = { A[1] - A[0], A[2] - A[1], A[0] - A[2] };
    V3 dB[3] = { B[1] - B[0], B[2] - B[1], B[0] - B[2] };
#pragma unroll
    for (int ii = 0; ii < 3; ++ii) {
#pragma unroll
        for (int jj = 0; jj < 3; ++jj) {
            V3 d1 = dA[ii], d2 = dB[jj];
            V3 r = A[ii] - B[jj];
            float a = dot(d1, d1), e = dot(d2, d2);
            float f = dot(d2, r), b = dot(d1, d2), c = dot(d1, r);
            float denom = a * e - b * b;
            bool par = denom < EPS_PAR;
            float rd = frcp(par ? 1.0f : denom);
            float s = (b * f - c * e) * rd;
            float t = (a * f - b * c) * rd;
            s = par ? 0.0f : s;
            float s_cl = clamp01(s), t_cl = clamp01(t);
            bool rec_t = (s_cl != s) || par;
            V3 rn = r + s_cl * d1;
            float t_new = clamp01(dot(rn, d2) * frcp(e));
            float t_fin = rec_t ? t_new : t_cl;
            bool rec_s = (t_cl != t) && (!par) && (s_cl == s);
            V3 rn2 = r - t_fin * d2;
            float s_new = (-dot(rn2, d1)) * frcp(a);
            float s_fin = rec_s ? clamp01(s_new) : s_cl;
            V3 diff = (A[ii] + s_fin * d1) - (B[jj] + t_fin * d2);
            mind2 = fminf(mind2, dot(diff, diff));
        }
    }
    return fmaxf(LOSS_EPS - sqrtf(mind2), 0.0f) * val;
}

__global__ void __launch_bounds__(256)
pen_loss_direct(const float* __restrict__ tris, const int2* __restrict__ idx,
                float* __restrict__ ws, int npairs, int F, int P) {
    int i = blockIdx.x * 256 + threadIdx.x;
    float pen = 0.0f, val = 0.0f;
    if (i < npairs) {
        int b = i / P;
        int2 ij = idx[i];
        val = (ij.x >= 0) ? 1.0f : 0.0f;
        const float* T1 = tris + ((size_t)b * (size_t)F + (size_t)max(ij.x, 0)) * 9;
        const float* T2 = tris + ((size_t)b * (size_t)F + (size_t)max(ij.y, 0)) * 9;
        float t1[9], t2[9];
#pragma unroll
        for (int k = 0; k < 9; ++k) t1[k] = T1[k];
#pragma unroll
        for (int k = 0; k < 9; ++k) t2[k] = T2[k];
        pen = pair_body_scalar(t1, t2, val);
    }
    block_reduce_atomic(pen, val, ws);
}

__global__ void finalize_kernel(const float* __restrict__ ws, float* __restrict__ out) {
    out[0] = ws[0] / fmaxf(ws[1], 1.0f);
}

extern "C" void kernel_launch(void* const* d_in, const int* in_sizes, int n_in,
                              void* d_out, int out_size, void* d_ws, size_t ws_size,
                              hipStream_t stream) {
    const float* tris = (const float*)d_in[0];
    const int* idx = (const int*)d_in[1];
    float* out = (float*)d_out;
    float* ws = (float*)d_ws;

    const int B = 4;
    int F = in_sizes[0] / (B * 9);      // 50000
    int npairs = in_sizes[1] / 2;       // 2,000,000
    int P = npairs / B;                 // 500,000
    int ntri = B * F;                   // 200,000

    hipMemsetAsync(d_ws, 0, 2 * sizeof(float), stream);

    size_t need = 256 + (size_t)ntri * 64;
    if (ws_size >= need) {
        float4* pack = (float4*)((char*)d_ws + 256);
        prep_kernel<<<(ntri + 255) / 256, 256, 0, stream>>>(tris, pack, ntri);
        int nwg = (npairs + PAIRS_PER_BLOCK - 1) / PAIRS_PER_BLOCK;   // 1954
        pen_loss_packed2<<<nwg, 256, 0, stream>>>(pack, (const int2*)idx, ws,
                                                  npairs, F, P, nwg);
    } else {
        int nwg = (npairs + 255) / 256;
        pen_loss_direct<<<nwg, 256, 0, stream>>>(tris, (const int2*)idx, ws,
                                                 npairs, F, P);
    }
    finalize_kernel<<<1, 1, 0, stream>>>(ws, out);
}

// Round 6
// 79.804 us; speedup vs baseline: 2.8964x; 1.1459x over previous
//
#include <hip/hip_runtime.h>

#define LOSS_EPS 0.001f
#define EPS_PAR 1e-12f
#define EPS_PT 1e-12f

typedef float f32x2 __attribute__((ext_vector_type(2)));
typedef int   i32x2 __attribute__((ext_vector_type(2)));

__device__ __forceinline__ f32x2 vmin2(f32x2 a, f32x2 b) { return __builtin_elementwise_min(a, b); }
__device__ __forceinline__ f32x2 vmax2(f32x2 a, f32x2 b) { return __builtin_elementwise_max(a, b); }
__device__ __forceinline__ f32x2 vclamp01(f32x2 v) {
    return vmin2(vmax2(v, (f32x2)0.0f), (f32x2)1.0f);
}
__device__ __forceinline__ f32x2 vrcp(f32x2 x) {
    f32x2 r; r.x = __builtin_amdgcn_rcpf(x.x); r.y = __builtin_amdgcn_rcpf(x.y); return r;
}
__device__ __forceinline__ f32x2 vsel(i32x2 m, f32x2 a, f32x2 b) {
    i32x2 ai = __builtin_bit_cast(i32x2, a);
    i32x2 bi = __builtin_bit_cast(i32x2, b);
    i32x2 r = (ai & m) | (bi & ~m);
    return __builtin_bit_cast(f32x2, r);
}

struct V3p { f32x2 x, y, z; };
__device__ __forceinline__ V3p operator-(V3p a, V3p b) { return {a.x - b.x, a.y - b.y, a.z - b.z}; }
__device__ __forceinline__ V3p operator+(V3p a, V3p b) { return {a.x + b.x, a.y + b.y, a.z + b.z}; }
__device__ __forceinline__ V3p operator*(f32x2 s, V3p a) { return {s * a.x, s * a.y, s * a.z}; }
__device__ __forceinline__ f32x2 dotp(V3p a, V3p b) { return a.x * b.x + a.y * b.y + a.z * b.z; }

__device__ __forceinline__ f32x2 edge_edge_d2(V3p p1, V3p d1, V3p p2, V3p d2,
                                              f32x2 a, f32x2 e, f32x2 ra, f32x2 re) {
    V3p r = p1 - p2;
    f32x2 f = dotp(d2, r);
    f32x2 b = dotp(d1, d2);
    f32x2 c = dotp(d1, r);
    f32x2 denom = a * e - b * b;
    i32x2 par = denom < (f32x2)EPS_PAR;
    f32x2 rd = vrcp(vsel(par, (f32x2)1.0f, denom));
    f32x2 s = (b * f - c * e) * rd;
    f32x2 t = (a * f - b * c) * rd;
    s = vsel(par, (f32x2)0.0f, s);
    f32x2 s_cl = vclamp01(s);
    f32x2 t_cl = vclamp01(t);
    i32x2 rec_t = (s_cl != s) | par;
    V3p r_new = r + s_cl * d1;
    f32x2 t_new = vclamp01(dotp(r_new, d2) * re);
    f32x2 t_fin = vsel(rec_t, t_new, t_cl);
    i32x2 rec_s = (t_cl != t) & ~par & (s_cl == s);
    V3p r_new2 = r - t_fin * d2;
    f32x2 s_new = (-dotp(r_new2, d1)) * ra;
    f32x2 s_fin = vsel(rec_s, vclamp01(s_new), s_cl);
    V3p c1 = p1 + s_fin * d1;
    V3p c2 = p2 + t_fin * d2;
    V3p diff = c1 - c2;
    return dotp(diff, diff);
}

__device__ __forceinline__ f32x2 ptri3_min_d2(V3p p0, V3p p1, V3p p2,
                                              V3p v0, V3p v1, V3p v2) {
    V3p e0 = v1 - v0;
    V3p e1 = v2 - v0;
    V3p e2t = v2 - v1;
    f32x2 a  = vmax2(dotp(e0, e0), (f32x2)EPS_PT);
    f32x2 b  = dotp(e0, e1);
    f32x2 c  = vmax2(dotp(e1, e1), (f32x2)EPS_PT);
    f32x2 a2 = vmax2(dotp(e2t, e2t), (f32x2)EPS_PT);
    f32x2 det = vmax2(a * c - b * b, (f32x2)EPS_PT);
    f32x2 ra = vrcp(a), rc = vrcp(c), ra2 = vrcp(a2), rdet = vrcp(det);

    f32x2 best = (f32x2)1e30f;
    V3p pts[3] = {p0, p1, p2};
#pragma unroll
    for (int k = 0; k < 3; ++k) {
        V3p p = pts[k];
        V3p w = p - v0;
        f32x2 d = dotp(e0, w);
        f32x2 e = dotp(e1, w);
        f32x2 f = dotp(w, w);
        f32x2 s = b * e - c * d;
        f32x2 t = b * d - a * e;
        i32x2 in_face = (s >= (f32x2)0.0f) & (t >= (f32x2)0.0f) & ((s + t) <= det);
        f32x2 s01 = vclamp01(d * ra);
        V3p u01 = w - s01 * e0;
        f32x2 d2_e01 = dotp(u01, u01);
        f32x2 t02 = vclamp01(e * rc);
        V3p u02 = w - t02 * e1;
        f32x2 d2_e02 = dotp(u02, u02);
        V3p w2 = p - v1;
        f32x2 dd2 = dotp(e2t, w2);
        f32x2 u12 = vclamp01(dd2 * ra2);
        V3p u12v = w2 - u12 * e2t;
        f32x2 d2_e12 = dotp(u12v, u12v);
        f32x2 d2_face = vmax2((f * det - (d * s + e * t)) * rdet, (f32x2)0.0f);
        f32x2 d2_edge = vmin2(vmin2(d2_e01, d2_e02), d2_e12);
        best = vmin2(best, vsel(in_face, d2_face, d2_edge));
    }
    return best;
}

// Packed body operating on pre-transposed T arrays (component 0 = even pair, 1 = odd pair).
__device__ __forceinline__ f32x2 body_from_T(const f32x2 T1[9], const f32x2 T2[9], f32x2 vmask) {
    V3p A[3]  = { {T1[0], T1[1], T1[2]}, {T1[3], T1[4], T1[5]}, {T1[6], T1[7], T1[8]} };
    V3p Ac[3] = { {T1[0], T1[3], T1[6]}, {T1[1], T1[4], T1[7]}, {T1[2], T1[5], T1[8]} };
    V3p B[3]  = { {T2[0], T2[1], T2[2]}, {T2[3], T2[4], T2[5]}, {T2[6], T2[7], T2[8]} };
    V3p Bc[3] = { {T2[0], T2[3], T2[6]}, {T2[1], T2[4], T2[7]}, {T2[2], T2[5], T2[8]} };

    f32x2 mind2 = (f32x2)1e30f;
    mind2 = vmin2(mind2, ptri3_min_d2(A[0], A[1], A[2], Bc[0], Bc[1], Bc[2]));
    mind2 = vmin2(mind2, ptri3_min_d2(B[0], B[1], B[2], Ac[0], Ac[1], Ac[2]));

    V3p dA[3] = { A[1] - A[0], A[2] - A[1], A[0] - A[2] };
    V3p dB[3] = { B[1] - B[0], B[2] - B[1], B[0] - B[2] };
    f32x2 la[3], lb[3], rla[3], rlb[3];
#pragma unroll
    for (int k = 0; k < 3; ++k) {
        la[k] = dotp(dA[k], dA[k]); rla[k] = vrcp(la[k]);
        lb[k] = dotp(dB[k], dB[k]); rlb[k] = vrcp(lb[k]);
    }
#pragma unroll
    for (int ii = 0; ii < 3; ++ii) {
#pragma unroll
        for (int jj = 0; jj < 3; ++jj) {
            mind2 = vmin2(mind2, edge_edge_d2(A[ii], dA[ii], B[jj], dB[jj],
                                              la[ii], lb[jj], rla[ii], rlb[jj]));
        }
    }
    f32x2 dist;
    dist.x = __builtin_sqrtf(mind2.x);
    dist.y = __builtin_sqrtf(mind2.y);
    return vmax2((f32x2)LOSS_EPS - dist, (f32x2)0.0f) * vmask;
}

__device__ __forceinline__ void block_reduce_atomic(float pen, float val, float* ws) {
#pragma unroll
    for (int off = 32; off > 0; off >>= 1) {
        pen += __shfl_down(pen, off);
        val += __shfl_down(val, off);
    }
    __shared__ float sp[4], sv[4];
    int wid = threadIdx.x >> 6;
    if ((threadIdx.x & 63) == 0) { sp[wid] = pen; sv[wid] = val; }
    __syncthreads();
    if (threadIdx.x == 0) {
        atomicAdd(&ws[0], sp[0] + sp[1] + sp[2] + sp[3]);
        atomicAdd(&ws[1], sv[0] + sv[1] + sv[2] + sv[3]);
    }
}

// Repack 9-float (36B) triangles into 64B-aligned slots (3 float4 used, 1 pad).
__global__ void __launch_bounds__(256)
prep_kernel(const float* __restrict__ tris, float4* __restrict__ pack, int ntri) {
    int g = blockIdx.x * 256 + threadIdx.x;
    if (g >= ntri) return;
    const float* s = tris + (size_t)g * 9;
    float t[9];
#pragma unroll
    for (int k = 0; k < 9; ++k) t[k] = s[k];
    float4* d = pack + (size_t)g * 4;
    d[0] = make_float4(t[0], t[1], t[2], t[3]);
    d[1] = make_float4(t[4], t[5], t[6], t[7]);
    d[2] = make_float4(t[8], 0.0f, 0.0f, 0.0f);
}

#define PPT 8                         // pairs per thread (4 packed bodies)
#define PAIRS_PER_BLOCK (256 * PPT)   // 2048

__global__ void __launch_bounds__(256)
pen_loss_pipe2(const float4* __restrict__ pack, const int* __restrict__ idx,
               float* __restrict__ ws, int npairs, int F, int P, int nwg) {
    // Bijective XCD chunk swizzle (m204).
    int pb = blockIdx.x;
    int x = pb & 7, j = pb >> 3;
    int q8 = nwg >> 3, r8 = nwg & 7;
    int start = (x < r8) ? x * (q8 + 1) : r8 * (q8 + 1) + (x - r8) * q8;
    int lb = start + j;
    int tid = (int)threadIdx.x;
    int p0 = lb * PAIRS_PER_BLOCK + tid;

    // 1) All idx loads upfront (coalesced, nontemporal: keep L2 for the table).
    int o1[PPT], o2[PPT];
    float vm[PPT];
#pragma unroll
    for (int k = 0; k < PPT; ++k) {
        int p = p0 + k * 256;
        int pc = min(p, npairs - 1);
        long long pr = __builtin_nontemporal_load((const long long*)idx + pc);
        int rx = (int)(pr & 0xffffffffLL);
        int ry = (int)(pr >> 32);
        vm[k] = (p < npairs && rx >= 0) ? 1.0f : 0.0f;
        int b = (pc >= P) + (pc >= 2 * P) + (pc >= 3 * P);   // pc / P without idiv
        int base = b * F;
        o1[k] = (base + max(rx, 0)) * 4;
        o2[k] = (base + max(ry, 0)) * 4;
    }

    // Single 12-quad buffer: transpose frees it, then next body's loads refill it
    // while the ~1400-cycle packed body runs. All indices static.
    float4 qb_[12];

#define LOADBODY(m) do {                                                      \
        const int ev = 2 * (m), od = 2 * (m) + 1;                             \
        qb_[0] = pack[o1[ev]];     qb_[1] = pack[o1[ev] + 1];                 \
        qb_[2] = pack[o1[ev] + 2]; qb_[3] = pack[o2[ev]];                     \
        qb_[4] = pack[o2[ev] + 1]; qb_[5] = pack[o2[ev] + 2];                 \
        qb_[6] = pack[o1[od]];     qb_[7] = pack[o1[od] + 1];                 \
        qb_[8] = pack[o1[od] + 2]; qb_[9] = pack[o2[od]];                     \
        qb_[10] = pack[o2[od] + 1]; qb_[11] = pack[o2[od] + 2];               \
    } while (0)

#define PACKT(T1, T2) do {                                                    \
        T1[0] = (f32x2){qb_[0].x, qb_[6].x}; T1[1] = (f32x2){qb_[0].y, qb_[6].y}; \
        T1[2] = (f32x2){qb_[0].z, qb_[6].z}; T1[3] = (f32x2){qb_[0].w, qb_[6].w}; \
        T1[4] = (f32x2){qb_[1].x, qb_[7].x}; T1[5] = (f32x2){qb_[1].y, qb_[7].y}; \
        T1[6] = (f32x2){qb_[1].z, qb_[7].z}; T1[7] = (f32x2){qb_[1].w, qb_[7].w}; \
        T1[8] = (f32x2){qb_[2].x, qb_[8].x};                                      \
        T2[0] = (f32x2){qb_[3].x, qb_[9].x}; T2[1] = (f32x2){qb_[3].y, qb_[9].y}; \
        T2[2] = (f32x2){qb_[3].z, qb_[9].z}; T2[3] = (f32x2){qb_[3].w, qb_[9].w}; \
        T2[4] = (f32x2){qb_[4].x, qb_[10].x}; T2[5] = (f32x2){qb_[4].y, qb_[10].y}; \
        T2[6] = (f32x2){qb_[4].z, qb_[10].z}; T2[7] = (f32x2){qb_[4].w, qb_[10].w}; \
        T2[8] = (f32x2){qb_[5].x, qb_[11].x};                                     \
    } while (0)

    LOADBODY(0);
    f32x2 pen2 = (f32x2)0.0f;
#pragma unroll
    for (int m = 0; m < PPT / 2; ++m) {
        f32x2 T1[9], T2[9];
        PACKT(T1, T2);                     // consumes qb_ (waits loads), frees it
        if (m < PPT / 2 - 1) LOADBODY(m + 1);  // next body's gathers fly under the body
        f32x2 vmm = {vm[2 * m], vm[2 * m + 1]};
        pen2 += body_from_T(T1, T2, vmm);
    }
#undef LOADBODY
#undef PACKT

    float pen_s = pen2.x + pen2.y;
    float val_s = 0.0f;
#pragma unroll
    for (int k = 0; k < PPT; ++k) val_s += vm[k];
    block_reduce_atomic(pen_s, val_s, ws);
}

// -------- scalar fallback (workspace too small) --------
struct V3 { float x, y, z; };
__device__ __forceinline__ V3 operator-(V3 a, V3 b) { return {a.x - b.x, a.y - b.y, a.z - b.z}; }
__device__ __forceinline__ V3 operator+(V3 a, V3 b) { return {a.x + b.x, a.y + b.y, a.z + b.z}; }
__device__ __forceinline__ V3 operator*(float s, V3 a) { return {s * a.x, s * a.y, s * a.z}; }
__device__ __forceinline__ float dot(V3 a, V3 b) { return a.x * b.x + a.y * b.y + a.z * b.z; }
__device__ __forceinline__ float clamp01(float v) { return fminf(fmaxf(v, 0.0f), 1.0f); }
__device__ __forceinline__ float frcp(float x) { return __builtin_amdgcn_rcpf(x); }

__device__ float pair_body_scalar(const float t1[9], const float t2[9], float val) {
    V3 A[3]  = { {t1[0], t1[1], t1[2]}, {t1[3], t1[4], t1[5]}, {t1[6], t1[7], t1[8]} };
    V3 Ac[3] = { {t1[0], t1[3], t1[6]}, {t1[1], t1[4], t1[7]}, {t1[2], t1[5], t1[8]} };
    V3 B[3]  = { {t2[0], t2[1], t2[2]}, {t2[3], t2[4], t2[5]}, {t2[6], t2[7], t2[8]} };
    V3 Bc[3] = { {t2[0], t2[3], t2[6]}, {t2[1], t2[4], t2[7]}, {t2[2], t2[5], t2[8]} };
    float mind2 = 1e30f;
#pragma unroll
    for (int dir = 0; dir < 2; ++dir) {
        V3* P3 = dir ? B : A;
        V3* T3 = dir ? Ac : Bc;
        V3 e0 = T3[1] - T3[0], e1 = T3[2] - T3[0], e2t = T3[2] - T3[1];
        float a = fmaxf(dot(e0, e0), EPS_PT), b = dot(e0, e1);
        float c = fmaxf(dot(e1, e1), EPS_PT), a2 = fmaxf(dot(e2t, e2t), EPS_PT);
        float det = fmaxf(a * c - b * b, EPS_PT);
        float ra = frcp(a), rc = frcp(c), ra2 = frcp(a2), rdet = frcp(det);
#pragma unroll
        for (int k = 0; k < 3; ++k) {
            V3 p = P3[k];
            V3 w = p - T3[0];
            float d = dot(e0, w), e = dot(e1, w), f = dot(w, w);
            float s = b * e - c * d, t = b * d - a * e;
            bool in_face = (s >= 0.0f) && (t >= 0.0f) && (s + t <= det);
            float s01 = clamp01(d * ra);
            V3 u01 = w - s01 * e0;
            float t02 = clamp01(e * rc);
            V3 u02 = w - t02 * e1;
            V3 w2 = p - T3[1];
            float u12 = clamp01(dot(e2t, w2) * ra2);
            V3 u12v = w2 - u12 * e2t;
            float d2_face = fmaxf((f * det - (d * s + e * t)) * rdet, 0.0f);
            float d2_edge = fminf(fminf(dot(u01, u01), dot(u02, u02)), dot(u12v, u12v));
            mind2 = fminf(mind2, in_face ? d2_face : d2_edge);
        }
    }
    V3 dA[3] = { A[1] - A[0], A[2] - A[1], A[0] - A[2] };
    V3 dB[3] = { B[1] - B[0], B[2] - B[1], B[0] - B[2] };
#pragma unroll
    for (int ii = 0; ii < 3; ++ii) {
#pragma unroll
        for (int jj = 0; jj < 3; ++jj) {
            V3 d1 = dA[ii], d2 = dB[jj];
            V3 r = A[ii] - B[jj];
            float a = dot(d1, d1), e = dot(d2, d2);
            float f = dot(d2, r), b = dot(d1, d2), c = dot(d1, r);
            float denom = a * e - b * b;
            bool par = denom < EPS_PAR;
            float rd = frcp(par ? 1.0f : denom);
            float s = (b * f - c * e) * rd;
            float t = (a * f - b * c) * rd;
            s = par ? 0.0f : s;
            float s_cl = clamp01(s), t_cl = clamp01(t);
            bool rec_t = (s_cl != s) || par;
            V3 rn = r + s_cl * d1;
            float t_new = clamp01(dot(rn, d2) * frcp(e));
            float t_fin = rec_t ? t_new : t_cl;
            bool rec_s = (t_cl != t) && (!par) && (s_cl == s);
            V3 rn2 = r - t_fin * d2;
            float s_new = (-dot(rn2, d1)) * frcp(a);
            float s_fin = rec_s ? clamp01(s_new) : s_cl;
            V3 diff = (A[ii] + s_fin * d1) - (B[jj] + t_fin * d2);
            mind2 = fminf(mind2, dot(diff, diff));
        }
    }
    return fmaxf(LOSS_EPS - sqrtf(mind2), 0.0f) * val;
}

__global__ void __launch_bounds__(256)
pen_loss_direct(const float* __restrict__ tris, const int2* __restrict__ idx,
                float* __restrict__ ws, int npairs, int F, int P) {
    int i = blockIdx.x * 256 + threadIdx.x;
    float pen = 0.0f, val = 0.0f;
    if (i < npairs) {
        int b = i / P;
        int2 ij = idx[i];
        val = (ij.x >= 0) ? 1.0f : 0.0f;
        const float* T1 = tris + ((size_t)b * (size_t)F + (size_t)max(ij.x, 0)) * 9;
        const float* T2 = tris + ((size_t)b * (size_t)F + (size_t)max(ij.y, 0)) * 9;
        float t1[9], t2[9];
#pragma unroll
        for (int k = 0; k < 9; ++k) t1[k] = T1[k];
#pragma unroll
        for (int k = 0; k < 9; ++k) t2[k] = T2[k];
        pen = pair_body_scalar(t1, t2, val);
    }
    block_reduce_atomic(pen, val, ws);
}

__global__ void finalize_kernel(const float* __restrict__ ws, float* __restrict__ out) {
    out[0] = ws[0] / fmaxf(ws[1], 1.0f);
}

extern "C" void kernel_launch(void* const* d_in, const int* in_sizes, int n_in,
                              void* d_out, int out_size, void* d_ws, size_t ws_size,
                              hipStream_t stream) {
    const float* tris = (const float*)d_in[0];
    const int* idx = (const int*)d_in[1];
    float* out = (float*)d_out;
    float* ws = (float*)d_ws;

    const int B = 4;
    int F = in_sizes[0] / (B * 9);      // 50000
    int npairs = in_sizes[1] / 2;       // 2,000,000
    int P = npairs / B;                 // 500,000
    int ntri = B * F;                   // 200,000

    hipMemsetAsync(d_ws, 0, 2 * sizeof(float), stream);

    size_t need = 256 + (size_t)ntri * 64;
    if (ws_size >= need) {
        float4* pack = (float4*)((char*)d_ws + 256);
        prep_kernel<<<(ntri + 255) / 256, 256, 0, stream>>>(tris, pack, ntri);
        int nwg = (npairs + PAIRS_PER_BLOCK - 1) / PAIRS_PER_BLOCK;   // 977
        pen_loss_pipe2<<<nwg, 256, 0, stream>>>(pack, idx, ws,
                                                npairs, F, P, nwg);
    } else {
        int nwg = (npairs + 255) / 256;
        pen_loss_direct<<<nwg, 256, 0, stream>>>(tris, (const int2*)idx, ws,
                                                 npairs, F, P);
    }
    finalize_kernel<<<1, 1, 0, stream>>>(ws, out);
}